// Round 5
// baseline (297.878 us; speedup 1.0000x reference)
//
#include <hip/hip_runtime.h>
#include <hip/hip_bf16.h>

typedef unsigned short u16;
typedef unsigned int   u32;

typedef __attribute__((ext_vector_type(8))) __bf16 bf16x8;
typedef __attribute__((ext_vector_type(4))) float  f32x4;
typedef __attribute__((ext_vector_type(4))) u32    u32x4;

#define NN 4096
#define DD 128
#define EPS 1e-12f

#define KS 4            // split-K factor
#define BM 32           // rows per block
#define BK 128          // k per stage
#define KPER (NN / KS)  // 1024
#define LDK 136         // padded LDS row stride (u16), 272 B (16B-aligned)

static __device__ __forceinline__ u16 f2bf(float f) {
    union { float f; u32 u; } v; v.f = f;
    u32 r = v.u + 0x7fffu + ((v.u >> 16) & 1u);   // round-to-nearest-even
    return (u16)(r >> 16);
}
static __device__ __forceinline__ float bf2f(u16 u) {
    union { u32 i; float f; } v; v.i = (u32)u << 16; return v.f;
}

// --- bf16x2 atomic add: HW pk_add_bf16 if available, CAS fallback otherwise ---
template <typename T>
static __device__ __forceinline__ auto bf2_atomic_add(T* p, T v, int)
    -> decltype(unsafeAtomicAdd(p, v), void()) {
    unsafeAtomicAdd(p, v);
}
template <typename T>
static __device__ __forceinline__ void bf2_atomic_add(T* p, T v, long) {
    u32* w = (u32*)p;
    union { u32 i; T h; } av; av.h = v;
    float alo = bf2f((u16)(av.i & 0xffff));
    float ahi = bf2f((u16)(av.i >> 16));
    u32 old = *w, assumed;
    do {
        assumed = old;
        float lo = bf2f((u16)(assumed & 0xffff)) + alo;
        float hi = bf2f((u16)(assumed >> 16)) + ahi;
        u32 nv = (u32)f2bf(lo) | ((u32)f2bf(hi) << 16);
        old = atomicCAS(w, assumed, nv);
    } while (old != assumed);
}

// ---------------------------------------------------------------------------
// Edge kernel v2: 8 lanes per edge (8 edges per wave) for deep MLP.
// Each lane holds 12 x 16B loads in flight (192 B/lane, 12 KB/wave) vs 48 B
// in the 32-lane version; reduction is 3 shuffle steps instead of 5.
// val = exp(-||A[c]+case-A[t]||); packed-bf16 atomicAdd into att[t*N+c].
// ---------------------------------------------------------------------------
__global__ __launch_bounds__(256) void edge_kernel(
    const int* __restrict__ currents, const int* __restrict__ targets,
    const float* __restrict__ A, const float* __restrict__ cases,
    u16* __restrict__ att, int E)
{
    const int wave = threadIdx.x >> 6;
    const int l    = threadIdx.x & 63;
    const int sub  = l & 7;                      // lane within 8-lane group
    const int e    = blockIdx.x * 32 + wave * 8 + (l >> 3);
    if (e >= E) return;
    const int c = currents[e];
    const int t = targets[e];
    const float* hp = A + (size_t)c * DD + sub * 16;
    const float* gp = A + (size_t)t * DD + sub * 16;
    const float* qp = cases + (size_t)e * DD + sub * 16;
    f32x4 h0 = *(const f32x4*)(hp);
    f32x4 h1 = *(const f32x4*)(hp + 4);
    f32x4 h2 = *(const f32x4*)(hp + 8);
    f32x4 h3 = *(const f32x4*)(hp + 12);
    f32x4 g0 = *(const f32x4*)(gp);
    f32x4 g1 = *(const f32x4*)(gp + 4);
    f32x4 g2 = *(const f32x4*)(gp + 8);
    f32x4 g3 = *(const f32x4*)(gp + 12);
    f32x4 q0 = __builtin_nontemporal_load((const f32x4*)(qp));
    f32x4 q1 = __builtin_nontemporal_load((const f32x4*)(qp + 4));
    f32x4 q2 = __builtin_nontemporal_load((const f32x4*)(qp + 8));
    f32x4 q3 = __builtin_nontemporal_load((const f32x4*)(qp + 12));

    f32x4 d0 = h0 + q0 - g0;
    f32x4 d1 = h1 + q1 - g1;
    f32x4 d2 = h2 + q2 - g2;
    f32x4 d3 = h3 + q3 - g3;
    float s = d0.x*d0.x + d0.y*d0.y + d0.z*d0.z + d0.w*d0.w
            + d1.x*d1.x + d1.y*d1.y + d1.z*d1.z + d1.w*d1.w
            + d2.x*d2.x + d2.y*d2.y + d2.z*d2.z + d2.w*d2.w
            + d3.x*d3.x + d3.y*d3.y + d3.z*d3.z + d3.w*d3.w;
    s += __shfl_xor(s, 4, 64);
    s += __shfl_xor(s, 2, 64);
    s += __shfl_xor(s, 1, 64);
    if (sub == 0) {
        float val = __expf(-__fsqrt_rn(s));
        u16 b = f2bf(val);
        size_t off = (size_t)t * NN + c;
        union { u32 i; __hip_bfloat162 h2; } pk;
        pk.i = (c & 1) ? ((u32)b << 16) : (u32)b;
        bf2_atomic_add((__hip_bfloat162*)(att + (off & ~(size_t)1)), pk.h2, 0);
    }
}

// ---------------------------------------------------------------------------
// Transpose+convert: in [4096][128] fp32 -> out [128][4096] bf16
// ---------------------------------------------------------------------------
__global__ __launch_bounds__(256) void transpose_to_bf16(
    const float* __restrict__ in, u16* __restrict__ out)
{
    __shared__ __align__(16) u16 lds[128][40];
    const int k0 = blockIdx.x * 32;
    const int t = threadIdx.x;
#pragma unroll
    for (int i = 0; i < 4; ++i) {
        int f  = t + 256 * i;
        int kr = f >> 5;
        int n0 = (f & 31) * 4;
        float4 v = *(const float4*)(in + (size_t)(k0 + kr) * DD + n0);
        lds[n0 + 0][kr] = f2bf(v.x);
        lds[n0 + 1][kr] = f2bf(v.y);
        lds[n0 + 2][kr] = f2bf(v.z);
        lds[n0 + 3][kr] = f2bf(v.w);
    }
    __syncthreads();
    int n = t >> 1, h = t & 1;
    uint4 v0 = *(const uint4*)&lds[n][h * 16];
    uint4 v1 = *(const uint4*)&lds[n][h * 16 + 8];
    *(uint4*)(out + (size_t)n * NN + k0 + h * 16)     = v0;
    *(uint4*)(out + (size_t)n * NN + k0 + h * 16 + 8) = v1;
}

// ---------------------------------------------------------------------------
// Split-K skinny GEMM with 1-deep register pipeline:
//   part[ks] = Amat[m0:m0+32, ks*1024:(ks+1)*1024] @ B
// ABF16=false: Amat fp32 (W), converted to bf16 in staging.
// ABF16=true : Amat bf16 (att), staged directly.
// A-panel is read-once -> non-temporal loads.
// ROWSUM: accumulate fp32 row-sums of Amat into normsum (atomic, 4/addr).
// ---------------------------------------------------------------------------
template<bool ROWSUM, bool ABF16>
__global__ __launch_bounds__(512, 4) void gemm_splitk(
    const void* __restrict__ AmatV,
    const u16*  __restrict__ BT,      // [128][4096] bf16 (B^T)
    float* __restrict__ part,         // [KS][4096][128]
    float* __restrict__ normsum)      // [4096] (ROWSUM only)
{
    __shared__ __align__(16) u16 As[BM * LDK];   // 8.7 KB
    __shared__ __align__(16) u16 Bs[DD * LDK];   // 34.8 KB

    const int m0   = blockIdx.x * BM;
    const int ks   = blockIdx.y;
    const int kbeg = ks * KPER;
    const int t    = threadIdx.x;
    const int wave = t >> 6;
    const int lane = t & 63;
    const int quad = lane >> 4;
    const int l16  = lane & 15;

    // staging indices
    const int ar = t >> 4;   // 0..31 (A row)
    const int aq = t & 15;   // chunk within row
    const int bn = t >> 2;   // 0..127 (B row)
    const int bq = t & 3;    // 32-u16 chunk within row

    const float* Apf = (const float*)AmatV + (size_t)(m0 + ar) * NN + kbeg + aq * 4;
    const u16*   Aph = (const u16*)AmatV   + (size_t)(m0 + ar) * NN + kbeg + aq * 8;
    const u16*   Bp  = BT + (size_t)bn * NN + kbeg + bq * 32;

    // prologue: load tile 0 into registers
    f32x4 va0, va1; u32x4 vah;
    if constexpr (ABF16) {
        vah = __builtin_nontemporal_load((const u32x4*)Aph);
    } else {
        va0 = __builtin_nontemporal_load((const f32x4*)Apf);
        va1 = __builtin_nontemporal_load((const f32x4*)(Apf + 64));
    }
    uint4 vb0 = *(const uint4*)(Bp);
    uint4 vb1 = *(const uint4*)(Bp + 8);
    uint4 vb2 = *(const uint4*)(Bp + 16);
    uint4 vb3 = *(const uint4*)(Bp + 24);

    f32x4 acc0 = {0.f, 0.f, 0.f, 0.f};
    f32x4 acc1 = {0.f, 0.f, 0.f, 0.f};
    float rsum = 0.f;

    for (int kk = 0; kk < KPER; kk += BK) {
        // ---- store staged registers to LDS (vmcnt wait lands here) ----
        if constexpr (ABF16) {
            if (ROWSUM) {
#pragma unroll
            for (int j = 0; j < 4; ++j) {
                u32 w = vah[j];
                rsum += bf2f((u16)(w & 0xffff)) + bf2f((u16)(w >> 16));
            }
            }
            *(u32x4*)&As[ar * LDK + aq * 8] = vah;
        } else {
            if (ROWSUM) {
                rsum += (va0.x + va0.y) + (va0.z + va0.w)
                      + (va1.x + va1.y) + (va1.z + va1.w);
            }
            ushort4 u0, u1;
            u0.x = f2bf(va0.x); u0.y = f2bf(va0.y); u0.z = f2bf(va0.z); u0.w = f2bf(va0.w);
            u1.x = f2bf(va1.x); u1.y = f2bf(va1.y); u1.z = f2bf(va1.z); u1.w = f2bf(va1.w);
            *(ushort4*)&As[ar * LDK + aq * 4]      = u0;
            *(ushort4*)&As[ar * LDK + aq * 4 + 64] = u1;
        }
        *(uint4*)&Bs[bn * LDK + bq * 32]      = vb0;
        *(uint4*)&Bs[bn * LDK + bq * 32 + 8]  = vb1;
        *(uint4*)&Bs[bn * LDK + bq * 32 + 16] = vb2;
        *(uint4*)&Bs[bn * LDK + bq * 32 + 24] = vb3;
        __syncthreads();

        // ---- issue next tile's global loads (overlap with MFMA below) ----
        if (kk + BK < KPER) {
            int k1 = kk + BK;
            if constexpr (ABF16) {
                vah = __builtin_nontemporal_load((const u32x4*)(Aph + k1));
            } else {
                va0 = __builtin_nontemporal_load((const f32x4*)(Apf + k1));
                va1 = __builtin_nontemporal_load((const f32x4*)(Apf + k1 + 64));
            }
            vb0 = *(const uint4*)(Bp + k1);
            vb1 = *(const uint4*)(Bp + k1 + 8);
            vb2 = *(const uint4*)(Bp + k1 + 16);
            vb3 = *(const uint4*)(Bp + k1 + 24);
        }

        // ---- compute current tile from LDS ----
#pragma unroll
        for (int k2 = 0; k2 < 4; ++k2) {
            bf16x8 a0 = *(const bf16x8*)&As[l16 * LDK + k2 * 32 + quad * 8];
            bf16x8 a1 = *(const bf16x8*)&As[(16 + l16) * LDK + k2 * 32 + quad * 8];
            bf16x8 b  = *(const bf16x8*)&Bs[(wave * 16 + l16) * LDK + k2 * 32 + quad * 8];
            acc0 = __builtin_amdgcn_mfma_f32_16x16x32_bf16(a0, b, acc0, 0, 0, 0);
            acc1 = __builtin_amdgcn_mfma_f32_16x16x32_bf16(a1, b, acc1, 0, 0, 0);
        }
        __syncthreads();
    }

    // D layout: col = lane&15 (within wave's 16-col tile), row = quad*4+reg
    float* P = part + (size_t)ks * NN * DD;
#pragma unroll
    for (int r = 0; r < 4; ++r) {
        int row0 = m0 + quad * 4 + r;
        int col  = wave * 16 + l16;
        P[(size_t)row0 * DD + col]        = acc0[r];
        P[(size_t)(row0 + 16) * DD + col] = acc1[r];
    }

    if (ROWSUM) {
        // 16 threads (aq = 0..15) share row ar; reduce within the 16-lane group
#pragma unroll
        for (int m = 8; m; m >>= 1) rsum += __shfl_xor(rsum, m, 64);
        if ((t & 15) == 0) atomicAdd(normsum + m0 + ar, rsum);
    }
}

// ---------------------------------------------------------------------------
// feat = sum of KS partials
// ---------------------------------------------------------------------------
__global__ __launch_bounds__(256) void combine_feat(
    const float* __restrict__ part, float* __restrict__ feat)
{
    int i = blockIdx.x * 256 + threadIdx.x;   // float4 index, NN*DD/4 total
    const float4* p = (const float4*)part;
    const int S = NN * DD / 4;
    float4 a = p[i], b = p[i + S], c = p[i + 2 * S], d = p[i + 3 * S];
    float4 s;
    s.x = (a.x + b.x) + (c.x + d.x);
    s.y = (a.y + b.y) + (c.y + d.y);
    s.z = (a.z + b.z) + (c.z + d.z);
    s.w = (a.w + b.w) + (c.w + d.w);
    ((float4*)feat)[i] = s;
}

// ---------------------------------------------------------------------------
// out = (sum of KS partials) / (normsum[row] + EPS) + feat
// ---------------------------------------------------------------------------
__global__ __launch_bounds__(256) void combine_out(
    const float* __restrict__ part, const float* __restrict__ normsum,
    const float* __restrict__ feat, float* __restrict__ out)
{
    int i = blockIdx.x * 256 + threadIdx.x;   // float4 index
    int row = i >> 5;                          // 32 float4 per 128-col row
    const float4* p = (const float4*)part;
    const int S = NN * DD / 4;
    float4 a = p[i], b = p[i + S], c = p[i + 2 * S], d = p[i + 3 * S];
    float sc = 1.0f / (normsum[row] + EPS);
    float4 f = ((const float4*)feat)[i];
    float4 s;
    s.x = ((a.x + b.x) + (c.x + d.x)) * sc + f.x;
    s.y = ((a.y + b.y) + (c.y + d.y)) * sc + f.y;
    s.z = ((a.z + b.z) + (c.z + d.z)) * sc + f.z;
    s.w = ((a.w + b.w) + (c.w + d.w)) * sc + f.w;
    ((float4*)out)[i] = s;
}

// ---------------------------------------------------------------------------
extern "C" void kernel_launch(void* const* d_in, const int* in_sizes, int n_in,
                              void* d_out, int out_size, void* d_ws, size_t ws_size,
                              hipStream_t stream)
{
    const int*   currents = (const int*)d_in[0];
    const int*   targets  = (const int*)d_in[1];
    const float* acts     = (const float*)d_in[2];   // [4096][128]
    const float* cases    = (const float*)d_in[3];   // [E][128]
    const float* W        = (const float*)d_in[4];   // [4096][4096]
    float*       out      = (float*)d_out;           // [4096][128]
    const int E = in_sizes[0];

    // workspace layout
    char* ws = (char*)d_ws;
    u16*   att     = (u16*)ws;                                       // 32 MB (bf16)
    float* part    = (float*)(ws + (size_t)NN * NN * 2);             // KS*2 MB
    float* feat    = part + (size_t)KS * NN * DD;                    // 2 MB
    u16*   BT1     = (u16*)(feat + (size_t)NN * DD);                 // 1 MB
    u16*   BT2     = BT1 + (size_t)DD * NN;                          // 1 MB
    float* normsum = (float*)(BT2 + (size_t)DD * NN);                // 16 KB

    hipMemsetAsync(att, 0, (size_t)NN * NN * 2, stream);
    hipMemsetAsync(normsum, 0, (size_t)NN * 4, stream);

    // BT1 = bf16(acts^T)
    transpose_to_bf16<<<128, 256, 0, stream>>>(acts, BT1);

    // edge scatter (packed-bf16 atomics into bf16 att), 32 edges/block
    edge_kernel<<<(E + 31) / 32, 256, 0, stream>>>(currents, targets, acts, cases,
                                                   att, E);

    // feat = W @ acts  (split-K partials, then combine)
    gemm_splitk<false, false><<<dim3(NN / BM, KS), 512, 0, stream>>>(W, BT1, part, nullptr);
    combine_feat<<<NN * DD / 4 / 256, 256, 0, stream>>>(part, feat);

    // BT2 = bf16(feat^T)
    transpose_to_bf16<<<128, 256, 0, stream>>>(feat, BT2);

    // out = (att @ feat) / norm + feat   (gemm #2 also produces norm row-sums)
    gemm_splitk<true, true><<<dim3(NN / BM, KS), 512, 0, stream>>>(att, BT2, part, normsum);
    combine_out<<<NN * DD / 4 / 256, 256, 0, stream>>>(part, normsum, feat, out);
}

// Round 6
// 207.077 us; speedup vs baseline: 1.4385x; 1.4385x over previous
//
#include <hip/hip_runtime.h>
#include <hip/hip_bf16.h>

typedef unsigned short u16;
typedef unsigned int   u32;

typedef __attribute__((ext_vector_type(8))) __bf16 bf16x8;
typedef __attribute__((ext_vector_type(4))) float  f32x4;
typedef __attribute__((ext_vector_type(4))) u32    u32x4;

#define NN 4096
#define DD 128
#define EPS 1e-12f

#define KS 4            // split-K factor
#define BM 32           // rows per block
#define BK 128          // k per stage
#define KPER (NN / KS)  // 1024
#define LDK 136         // padded LDS row stride (u16), 272 B (16B-aligned)

static __device__ __forceinline__ u16 f2bf(float f) {
    union { float f; u32 u; } v; v.f = f;
    u32 r = v.u + 0x7fffu + ((v.u >> 16) & 1u);   // round-to-nearest-even
    return (u16)(r >> 16);
}
static __device__ __forceinline__ float bf2f(u16 u) {
    union { u32 i; float f; } v; v.i = (u32)u << 16; return v.f;
}

// --- bf16x2 atomic add: HW pk_add_bf16 if available, CAS fallback otherwise ---
template <typename T>
static __device__ __forceinline__ auto bf2_atomic_add(T* p, T v, int)
    -> decltype(unsafeAtomicAdd(p, v), void()) {
    unsafeAtomicAdd(p, v);
}
template <typename T>
static __device__ __forceinline__ void bf2_atomic_add(T* p, T v, long) {
    u32* w = (u32*)p;
    union { u32 i; T h; } av; av.h = v;
    float alo = bf2f((u16)(av.i & 0xffff));
    float ahi = bf2f((u16)(av.i >> 16));
    u32 old = *w, assumed;
    do {
        assumed = old;
        float lo = bf2f((u16)(assumed & 0xffff)) + alo;
        float hi = bf2f((u16)(assumed >> 16)) + ahi;
        u32 nv = (u32)f2bf(lo) | ((u32)f2bf(hi) << 16);
        old = atomicCAS(w, assumed, nv);
    } while (old != assumed);
}

// ---------------------------------------------------------------------------
// Edge kernel (r3 structure, unroll x2): 32 lanes per edge, each 32-lane
// group processes TWO independent edges (e, e+8). Coalescing identical to
// r3 (lane i -> base + i*16B, contiguous 512B per half-wave); per-lane
// in-flight bytes double 48->96B, index/reduce overhead amortizes over 2
// edges. val = exp(-||A[c]+case-A[t]||); packed-bf16 atomic into att.
// ---------------------------------------------------------------------------
__global__ __launch_bounds__(256) void edge_kernel(
    const int* __restrict__ currents, const int* __restrict__ targets,
    const float* __restrict__ A, const float* __restrict__ cases,
    u16* __restrict__ att, int E)
{
    const int slot = threadIdx.x >> 5;     // 0..7
    const int l    = threadIdx.x & 31;
    const int e0   = blockIdx.x * 16 + slot;
    const int e1   = e0 + 8;
    const bool v0 = e0 < E, v1 = e1 < E;

    int c0 = 0, t0 = 0, c1 = 0, t1 = 0;
    if (v0) { c0 = currents[e0]; t0 = targets[e0]; }
    if (v1) { c1 = currents[e1]; t1 = targets[e1]; }

    f32x4 h0 = {}, g0 = {}, q0 = {}, h1 = {}, g1 = {}, q1 = {};
    if (v0) {
        h0 = *(const f32x4*)(A + (size_t)c0 * DD + l * 4);
        g0 = *(const f32x4*)(A + (size_t)t0 * DD + l * 4);
        q0 = __builtin_nontemporal_load((const f32x4*)(cases + (size_t)e0 * DD + l * 4));
    }
    if (v1) {
        h1 = *(const f32x4*)(A + (size_t)c1 * DD + l * 4);
        g1 = *(const f32x4*)(A + (size_t)t1 * DD + l * 4);
        q1 = __builtin_nontemporal_load((const f32x4*)(cases + (size_t)e1 * DD + l * 4));
    }

    f32x4 d0 = h0 + q0 - g0;
    f32x4 d1 = h1 + q1 - g1;
    float s0 = d0.x * d0.x + d0.y * d0.y + d0.z * d0.z + d0.w * d0.w;
    float s1 = d1.x * d1.x + d1.y * d1.y + d1.z * d1.z + d1.w * d1.w;
#pragma unroll
    for (int m = 16; m; m >>= 1) {
        s0 += __shfl_xor(s0, m, 64);
        s1 += __shfl_xor(s1, m, 64);
    }
    if (l == 0) {
        if (v0) {
            float val = __expf(-__fsqrt_rn(s0));
            u16 b = f2bf(val);
            size_t off = (size_t)t0 * NN + c0;
            union { u32 i; __hip_bfloat162 h2; } pk;
            pk.i = (c0 & 1) ? ((u32)b << 16) : (u32)b;
            bf2_atomic_add((__hip_bfloat162*)(att + (off & ~(size_t)1)), pk.h2, 0);
        }
        if (v1) {
            float val = __expf(-__fsqrt_rn(s1));
            u16 b = f2bf(val);
            size_t off = (size_t)t1 * NN + c1;
            union { u32 i; __hip_bfloat162 h2; } pk;
            pk.i = (c1 & 1) ? ((u32)b << 16) : (u32)b;
            bf2_atomic_add((__hip_bfloat162*)(att + (off & ~(size_t)1)), pk.h2, 0);
        }
    }
}

// ---------------------------------------------------------------------------
// Transpose+convert: in [4096][128] fp32 -> out [128][4096] bf16
// ---------------------------------------------------------------------------
__global__ __launch_bounds__(256) void transpose_to_bf16(
    const float* __restrict__ in, u16* __restrict__ out)
{
    __shared__ __align__(16) u16 lds[128][40];
    const int k0 = blockIdx.x * 32;
    const int t = threadIdx.x;
#pragma unroll
    for (int i = 0; i < 4; ++i) {
        int f  = t + 256 * i;
        int kr = f >> 5;
        int n0 = (f & 31) * 4;
        float4 v = *(const float4*)(in + (size_t)(k0 + kr) * DD + n0);
        lds[n0 + 0][kr] = f2bf(v.x);
        lds[n0 + 1][kr] = f2bf(v.y);
        lds[n0 + 2][kr] = f2bf(v.z);
        lds[n0 + 3][kr] = f2bf(v.w);
    }
    __syncthreads();
    int n = t >> 1, h = t & 1;
    uint4 v0 = *(const uint4*)&lds[n][h * 16];
    uint4 v1 = *(const uint4*)&lds[n][h * 16 + 8];
    *(uint4*)(out + (size_t)n * NN + k0 + h * 16)     = v0;
    *(uint4*)(out + (size_t)n * NN + k0 + h * 16 + 8) = v1;
}

// ---------------------------------------------------------------------------
// Split-K skinny GEMM with 1-deep register pipeline:
//   part[ks] = Amat[m0:m0+32, ks*1024:(ks+1)*1024] @ B
// ABF16=false: Amat fp32 (W), converted to bf16 in staging.
// ABF16=true : Amat bf16 (att), staged directly.
// A-panel is read-once -> non-temporal loads.
// ROWSUM: accumulate fp32 row-sums of Amat into normsum (atomic, 4/addr).
// ---------------------------------------------------------------------------
template<bool ROWSUM, bool ABF16>
__global__ __launch_bounds__(512, 4) void gemm_splitk(
    const void* __restrict__ AmatV,
    const u16*  __restrict__ BT,      // [128][4096] bf16 (B^T)
    float* __restrict__ part,         // [KS][4096][128]
    float* __restrict__ normsum)      // [4096] (ROWSUM only)
{
    __shared__ __align__(16) u16 As[BM * LDK];   // 8.7 KB
    __shared__ __align__(16) u16 Bs[DD * LDK];   // 34.8 KB

    const int m0   = blockIdx.x * BM;
    const int ks   = blockIdx.y;
    const int kbeg = ks * KPER;
    const int t    = threadIdx.x;
    const int wave = t >> 6;
    const int lane = t & 63;
    const int quad = lane >> 4;
    const int l16  = lane & 15;

    // staging indices
    const int ar = t >> 4;   // 0..31 (A row)
    const int aq = t & 15;   // chunk within row
    const int bn = t >> 2;   // 0..127 (B row)
    const int bq = t & 3;    // 32-u16 chunk within row

    const float* Apf = (const float*)AmatV + (size_t)(m0 + ar) * NN + kbeg + aq * 4;
    const u16*   Aph = (const u16*)AmatV   + (size_t)(m0 + ar) * NN + kbeg + aq * 8;
    const u16*   Bp  = BT + (size_t)bn * NN + kbeg + bq * 32;

    // prologue: load tile 0 into registers
    f32x4 va0, va1; u32x4 vah;
    if constexpr (ABF16) {
        vah = __builtin_nontemporal_load((const u32x4*)Aph);
    } else {
        va0 = __builtin_nontemporal_load((const f32x4*)Apf);
        va1 = __builtin_nontemporal_load((const f32x4*)(Apf + 64));
    }
    uint4 vb0 = *(const uint4*)(Bp);
    uint4 vb1 = *(const uint4*)(Bp + 8);
    uint4 vb2 = *(const uint4*)(Bp + 16);
    uint4 vb3 = *(const uint4*)(Bp + 24);

    f32x4 acc0 = {0.f, 0.f, 0.f, 0.f};
    f32x4 acc1 = {0.f, 0.f, 0.f, 0.f};
    float rsum = 0.f;

    for (int kk = 0; kk < KPER; kk += BK) {
        // ---- store staged registers to LDS (vmcnt wait lands here) ----
        if constexpr (ABF16) {
            if (ROWSUM) {
#pragma unroll
            for (int j = 0; j < 4; ++j) {
                u32 w = vah[j];
                rsum += bf2f((u16)(w & 0xffff)) + bf2f((u16)(w >> 16));
            }
            }
            *(u32x4*)&As[ar * LDK + aq * 8] = vah;
        } else {
            if (ROWSUM) {
                rsum += (va0.x + va0.y) + (va0.z + va0.w)
                      + (va1.x + va1.y) + (va1.z + va1.w);
            }
            ushort4 u0, u1;
            u0.x = f2bf(va0.x); u0.y = f2bf(va0.y); u0.z = f2bf(va0.z); u0.w = f2bf(va0.w);
            u1.x = f2bf(va1.x); u1.y = f2bf(va1.y); u1.z = f2bf(va1.z); u1.w = f2bf(va1.w);
            *(ushort4*)&As[ar * LDK + aq * 4]      = u0;
            *(ushort4*)&As[ar * LDK + aq * 4 + 64] = u1;
        }
        *(uint4*)&Bs[bn * LDK + bq * 32]      = vb0;
        *(uint4*)&Bs[bn * LDK + bq * 32 + 8]  = vb1;
        *(uint4*)&Bs[bn * LDK + bq * 32 + 16] = vb2;
        *(uint4*)&Bs[bn * LDK + bq * 32 + 24] = vb3;
        __syncthreads();

        // ---- issue next tile's global loads (overlap with MFMA below) ----
        if (kk + BK < KPER) {
            int k1 = kk + BK;
            if constexpr (ABF16) {
                vah = __builtin_nontemporal_load((const u32x4*)(Aph + k1));
            } else {
                va0 = __builtin_nontemporal_load((const f32x4*)(Apf + k1));
                va1 = __builtin_nontemporal_load((const f32x4*)(Apf + k1 + 64));
            }
            vb0 = *(const uint4*)(Bp + k1);
            vb1 = *(const uint4*)(Bp + k1 + 8);
            vb2 = *(const uint4*)(Bp + k1 + 16);
            vb3 = *(const uint4*)(Bp + k1 + 24);
        }

        // ---- compute current tile from LDS ----
#pragma unroll
        for (int k2 = 0; k2 < 4; ++k2) {
            bf16x8 a0 = *(const bf16x8*)&As[l16 * LDK + k2 * 32 + quad * 8];
            bf16x8 a1 = *(const bf16x8*)&As[(16 + l16) * LDK + k2 * 32 + quad * 8];
            bf16x8 b  = *(const bf16x8*)&Bs[(wave * 16 + l16) * LDK + k2 * 32 + quad * 8];
            acc0 = __builtin_amdgcn_mfma_f32_16x16x32_bf16(a0, b, acc0, 0, 0, 0);
            acc1 = __builtin_amdgcn_mfma_f32_16x16x32_bf16(a1, b, acc1, 0, 0, 0);
        }
        __syncthreads();
    }

    // D layout: col = lane&15 (within wave's 16-col tile), row = quad*4+reg
    float* P = part + (size_t)ks * NN * DD;
#pragma unroll
    for (int r = 0; r < 4; ++r) {
        int row0 = m0 + quad * 4 + r;
        int col  = wave * 16 + l16;
        P[(size_t)row0 * DD + col]        = acc0[r];
        P[(size_t)(row0 + 16) * DD + col] = acc1[r];
    }

    if (ROWSUM) {
        // 16 threads (aq = 0..15) share row ar; reduce within the 16-lane group
#pragma unroll
        for (int m = 8; m; m >>= 1) rsum += __shfl_xor(rsum, m, 64);
        if ((t & 15) == 0) atomicAdd(normsum + m0 + ar, rsum);
    }
}

// ---------------------------------------------------------------------------
// feat = sum of KS partials
// ---------------------------------------------------------------------------
__global__ __launch_bounds__(256) void combine_feat(
    const float* __restrict__ part, float* __restrict__ feat)
{
    int i = blockIdx.x * 256 + threadIdx.x;   // float4 index, NN*DD/4 total
    const float4* p = (const float4*)part;
    const int S = NN * DD / 4;
    float4 a = p[i], b = p[i + S], c = p[i + 2 * S], d = p[i + 3 * S];
    float4 s;
    s.x = (a.x + b.x) + (c.x + d.x);
    s.y = (a.y + b.y) + (c.y + d.y);
    s.z = (a.z + b.z) + (c.z + d.z);
    s.w = (a.w + b.w) + (c.w + d.w);
    ((float4*)feat)[i] = s;
}

// ---------------------------------------------------------------------------
// out = (sum of KS partials) / (normsum[row] + EPS) + feat
// ---------------------------------------------------------------------------
__global__ __launch_bounds__(256) void combine_out(
    const float* __restrict__ part, const float* __restrict__ normsum,
    const float* __restrict__ feat, float* __restrict__ out)
{
    int i = blockIdx.x * 256 + threadIdx.x;   // float4 index
    int row = i >> 5;                          // 32 float4 per 128-col row
    const float4* p = (const float4*)part;
    const int S = NN * DD / 4;
    float4 a = p[i], b = p[i + S], c = p[i + 2 * S], d = p[i + 3 * S];
    float sc = 1.0f / (normsum[row] + EPS);
    float4 f = ((const float4*)feat)[i];
    float4 s;
    s.x = ((a.x + b.x) + (c.x + d.x)) * sc + f.x;
    s.y = ((a.y + b.y) + (c.y + d.y)) * sc + f.y;
    s.z = ((a.z + b.z) + (c.z + d.z)) * sc + f.z;
    s.w = ((a.w + b.w) + (c.w + d.w)) * sc + f.w;
    ((float4*)out)[i] = s;
}

// ---------------------------------------------------------------------------
extern "C" void kernel_launch(void* const* d_in, const int* in_sizes, int n_in,
                              void* d_out, int out_size, void* d_ws, size_t ws_size,
                              hipStream_t stream)
{
    const int*   currents = (const int*)d_in[0];
    const int*   targets  = (const int*)d_in[1];
    const float* acts     = (const float*)d_in[2];   // [4096][128]
    const float* cases    = (const float*)d_in[3];   // [E][128]
    const float* W        = (const float*)d_in[4];   // [4096][4096]
    float*       out      = (float*)d_out;           // [4096][128]
    const int E = in_sizes[0];

    // workspace layout
    char* ws = (char*)d_ws;
    u16*   att     = (u16*)ws;                                       // 32 MB (bf16)
    float* part    = (float*)(ws + (size_t)NN * NN * 2);             // KS*2 MB
    float* feat    = part + (size_t)KS * NN * DD;                    // 2 MB
    u16*   BT1     = (u16*)(feat + (size_t)NN * DD);                 // 1 MB
    u16*   BT2     = BT1 + (size_t)DD * NN;                          // 1 MB
    float* normsum = (float*)(BT2 + (size_t)DD * NN);                // 16 KB

    hipMemsetAsync(att, 0, (size_t)NN * NN * 2, stream);
    hipMemsetAsync(normsum, 0, (size_t)NN * 4, stream);

    // BT1 = bf16(acts^T)
    transpose_to_bf16<<<128, 256, 0, stream>>>(acts, BT1);

    // edge scatter (packed-bf16 atomics into bf16 att), 16 edges/block
    edge_kernel<<<(E + 15) / 16, 256, 0, stream>>>(currents, targets, acts, cases,
                                                   att, E);

    // feat = W @ acts  (split-K partials, then combine)
    gemm_splitk<false, false><<<dim3(NN / BM, KS), 512, 0, stream>>>(W, BT1, part, nullptr);
    combine_feat<<<NN * DD / 4 / 256, 256, 0, stream>>>(part, feat);

    // BT2 = bf16(feat^T)
    transpose_to_bf16<<<128, 256, 0, stream>>>(feat, BT2);

    // out = (att @ feat) / norm + feat   (gemm #2 also produces norm row-sums)
    gemm_splitk<true, true><<<dim3(NN / BM, KS), 512, 0, stream>>>(att, BT2, part, normsum);
    combine_out<<<NN * DD / 4 / 256, 256, 0, stream>>>(part, normsum, feat, out);
}